// Round 4
// baseline (141.876 us; speedup 1.0000x reference)
//
#include <hip/hip_runtime.h>

typedef __bf16 bf16x8 __attribute__((ext_vector_type(8)));
typedef float  f32x4  __attribute__((ext_vector_type(4)));

#define CC 64
#define HWSZ 4096
#define CHWSZ 262144
#define NE 512
#define NPIX 131072
#define PIXB 128
#define EPS_MARGIN 0.01f

#define ET_OFF 0            // 512 codes * 256 B (hi[64]|lo[64] bf16) = 131072
#define E2_OFF 131072       // 512 * 4
#define HIST_OFF 133120     // 512 * 4
#define BATCH_OFF 135168    // 32 * 4

__device__ __forceinline__ float bf2f(unsigned short u) {
    unsigned int x = ((unsigned int)u) << 16;
    return __builtin_bit_cast(float, x);
}
__device__ __forceinline__ unsigned short f2bf(float f) {
    unsigned int x = __builtin_bit_cast(unsigned int, f);
    unsigned int r = x + 0x7fffu + ((x >> 16) & 1u);
    return (unsigned short)(r >> 16);
}

// ---- init: exact e2[512]; embed^T hi/lo planes [code][hi64|lo64] bf16; zero hist/batch ----
__global__ __launch_bounds__(512) void vq_init(const float* __restrict__ eg, char* __restrict__ ws) {
    __shared__ float se[CC * 513];          // stride 513 kills transpose bank conflicts
    const int tid = threadIdx.x;
    for (int i = tid; i < CC * NE; i += 512) se[(i >> 9) * 513 + (i & 511)] = eg[i];
    __syncthreads();
    // exact e2 (numpy axis-0 sequential reduce) — must match recheck arithmetic
    float s = 0.f;
    #pragma unroll 8
    for (int k = 0; k < CC; ++k) { float v = se[k * 513 + tid]; s = __fadd_rn(s, __fmul_rn(v, v)); }
    ((float*)(ws + E2_OFF))[tid] = s;
    unsigned int* et32 = (unsigned int*)(ws + ET_OFF);
    #pragma unroll 4
    for (int it = 0; it < 64; ++it) {
        int idx = tid + it * 512;
        int n = idx >> 6;
        int kk2 = (idx & 63) << 1;
        int k = kk2 & 63;
        float v0 = se[k * 513 + n], v1 = se[(k + 1) * 513 + n];
        unsigned short c0, c1;
        if (kk2 < 64) { c0 = f2bf(v0); c1 = f2bf(v1); }
        else {
            unsigned short h0 = f2bf(v0), h1 = f2bf(v1);
            c0 = f2bf(__fsub_rn(v0, bf2f(h0)));
            c1 = f2bf(__fsub_rn(v1, bf2f(h1)));
        }
        et32[idx] = (unsigned int)c0 | ((unsigned int)c1 << 16);
    }
    ((unsigned int*)(ws + HIST_OFF))[tid] = 0u;
    if (tid < 32) ((float*)(ws + BATCH_OFF))[tid] = 0.f;
}

// ---- main: split-bf16 MFMA argmin (B direct from L2) + margin recheck + quantize ----
__global__ __launch_bounds__(256, 4) void vq_main(const float* __restrict__ xg,
                                                  const float* __restrict__ eg,
                                                  float* __restrict__ outg,
                                                  char* __restrict__ ws) {
    __shared__ __align__(16) char xtb[PIXB * 256];   // [pixel][hi64|lo64] bf16, XOR-swizzled
    __shared__ float e2s[NE];
    __shared__ int idxs[PIXB];
    __shared__ unsigned int hist[NE];
    __shared__ float wsum[4];
    __shared__ int nflag;
    __shared__ int flist[PIXB];
    __shared__ float xp[CC];
    __shared__ float redv[4];
    __shared__ int redi[4];

    const int tid  = threadIdx.x;
    const int lane = tid & 63;
    const int wv   = tid >> 6;
    const int l15  = lane & 15;
    const int l4   = lane >> 4;
    const int pix0 = blockIdx.x * PIXB;
    const int bb   = pix0 >> 12;
    const int hw0  = pix0 & 4095;
    const size_t xbase = (size_t)bb * CHWSZ + hw0;

    if (tid == 0) nflag = 0;

    // stage x: thread owns pixel p, k-half h; 8 coalesced scalar loads per q-iter,
    // split to bf16 hi/lo, packed as two ds_write_b128
    {
        const int p = tid & 127, h = tid >> 7;
        const int sw = (p & 15) << 4;
        #pragma unroll
        for (int q = 0; q < 4; ++q) {
            int k0 = h * 32 + q * 8;
            float v[8];
            #pragma unroll
            for (int j = 0; j < 8; ++j) v[j] = xg[xbase + (size_t)(k0 + j) * HWSZ + p];
            unsigned int hw_[4], lw_[4];
            #pragma unroll
            for (int j = 0; j < 4; ++j) {
                unsigned short h0 = f2bf(v[2 * j]), h1 = f2bf(v[2 * j + 1]);
                unsigned short o0 = f2bf(__fsub_rn(v[2 * j], bf2f(h0)));
                unsigned short o1 = f2bf(__fsub_rn(v[2 * j + 1], bf2f(h1)));
                hw_[j] = (unsigned int)h0 | ((unsigned int)h1 << 16);
                lw_[j] = (unsigned int)o0 | ((unsigned int)o1 << 16);
            }
            *(uint4*)(xtb + ((p * 256 + 2 * k0) ^ sw)) = (uint4){hw_[0], hw_[1], hw_[2], hw_[3]};
            *(uint4*)(xtb + ((p * 256 + 128 + 2 * k0) ^ sw)) = (uint4){lw_[0], lw_[1], lw_[2], lw_[3]};
        }
    }
    {
        const float* e2g = (const float*)(ws + E2_OFF);
        for (int t = tid; t < NE; t += 256) { e2s[t] = e2g[t]; hist[t] = 0u; }
    }
    __syncthreads();

    // A fragments (hi and lo), 2 m-tiles per wave — conflict-free swizzled reads
    bf16x8 ah[2][2], al[2][2];
    #pragma unroll
    for (int mt = 0; mt < 2; ++mt) {
        int prow = (2 * wv + mt) * 16 + l15;
        int sw = (prow & 15) << 4;
        #pragma unroll
        for (int kh = 0; kh < 2; ++kh) {
            ah[mt][kh] = *(const bf16x8*)(xtb + ((prow * 256 + kh * 64 + l4 * 16) ^ sw));
            al[mt][kh] = *(const bf16x8*)(xtb + ((prow * 256 + 128 + kh * 64 + l4 * 16) ^ sw));
        }
    }

    float minv[2][4], min2v[2][4];
    int   mini[2][4];
    #pragma unroll
    for (int mt = 0; mt < 2; ++mt)
        #pragma unroll
        for (int r = 0; r < 4; ++r) { minv[mt][r] = 3.4e38f; min2v[mt][r] = 3.4e38f; mini[mt][r] = 0; }

    const char* etw = ws + ET_OFF;

    // no barriers in this loop: B comes straight from L1/L2 (shared by all blocks)
    for (int ct = 0; ct < 4; ++ct) {
        #pragma unroll
        for (int nt = 0; nt < 8; ++nt) {
            const int code = ct * 128 + nt * 16 + l15;
            const char* bp = etw + ((size_t)code << 8) + l4 * 16;
            bf16x8 bh0 = *(const bf16x8*)(bp);
            bf16x8 bh1 = *(const bf16x8*)(bp + 64);
            bf16x8 bl0 = *(const bf16x8*)(bp + 128);
            bf16x8 bl1 = *(const bf16x8*)(bp + 192);
            float e2v = e2s[code];
            #pragma unroll
            for (int mt = 0; mt < 2; ++mt) {
                f32x4 acc = (f32x4){0.f, 0.f, 0.f, 0.f};
                acc = __builtin_amdgcn_mfma_f32_16x16x32_bf16(ah[mt][0], bh0, acc, 0, 0, 0);
                acc = __builtin_amdgcn_mfma_f32_16x16x32_bf16(ah[mt][1], bh1, acc, 0, 0, 0);
                acc = __builtin_amdgcn_mfma_f32_16x16x32_bf16(ah[mt][0], bl0, acc, 0, 0, 0);
                acc = __builtin_amdgcn_mfma_f32_16x16x32_bf16(ah[mt][1], bl1, acc, 0, 0, 0);
                acc = __builtin_amdgcn_mfma_f32_16x16x32_bf16(al[mt][0], bh0, acc, 0, 0, 0);
                acc = __builtin_amdgcn_mfma_f32_16x16x32_bf16(al[mt][1], bh1, acc, 0, 0, 0);
                #pragma unroll
                for (int r = 0; r < 4; ++r) {
                    float d = __fmaf_rn(-2.f, acc[r], e2v);
                    bool lt = d < minv[mt][r];
                    min2v[mt][r] = fminf(min2v[mt][r], fmaxf(d, minv[mt][r]));
                    minv[mt][r] = lt ? d : minv[mt][r];
                    mini[mt][r] = lt ? code : mini[mt][r];
                }
            }
        }
    }

    // 16-lane argmin reduce with second-min tracking and first-index tie-break
    #pragma unroll
    for (int m = 1; m < 16; m <<= 1) {
        #pragma unroll
        for (int mt = 0; mt < 2; ++mt)
            #pragma unroll
            for (int r = 0; r < 4; ++r) {
                float ov  = __shfl_xor(minv[mt][r], m, 64);
                int   oi  = __shfl_xor(mini[mt][r], m, 64);
                float ov2 = __shfl_xor(min2v[mt][r], m, 64);
                bool sel = (ov < minv[mt][r]) || (ov == minv[mt][r] && oi < mini[mt][r]);
                float big = sel ? minv[mt][r] : ov;
                min2v[mt][r] = fminf(fminf(min2v[mt][r], ov2), big);
                minv[mt][r] = sel ? ov : minv[mt][r];
                mini[mt][r] = sel ? oi : mini[mt][r];
            }
    }
    if (l15 == 0) {
        #pragma unroll
        for (int mt = 0; mt < 2; ++mt)
            #pragma unroll
            for (int r = 0; r < 4; ++r) {
                int p = (2 * wv + mt) * 16 + l4 * 4 + r;
                idxs[p] = mini[mt][r];
                if (min2v[mt][r] - minv[mt][r] < EPS_MARGIN) {
                    int pos = atomicAdd(&nflag, 1);
                    flist[pos] = p;
                }
            }
    }
    __syncthreads();

    // exact recheck for near-tie pixels — bit-identical to the verified fp32 arithmetic
    const int nf = nflag;
    for (int f = 0; f < nf; ++f) {
        int p = flist[f];
        if (tid < CC) xp[tid] = xg[xbase + (size_t)tid * HWSZ + p];
        __syncthreads();
        float rr[8];
        #pragma unroll
        for (int u = 0; u < 8; ++u) { float v = xp[u]; rr[u] = __fmul_rn(v, v); }
        #pragma unroll
        for (int t2 = 1; t2 < 8; ++t2)
            #pragma unroll
            for (int u = 0; u < 8; ++u) { float v = xp[t2 * 8 + u]; rr[u] = __fadd_rn(rr[u], __fmul_rn(v, v)); }
        float f2 = __fadd_rn(__fadd_rn(__fadd_rn(rr[0], rr[1]), __fadd_rn(rr[2], rr[3])),
                             __fadd_rn(__fadd_rn(rr[4], rr[5]), __fadd_rn(rr[6], rr[7])));
        float best = 3.4e38f; int bidx = 0;
        const float* e2g = (const float*)(ws + E2_OFF);
        #pragma unroll
        for (int h = 0; h < 2; ++h) {
            int c = h * 256 + tid;
            float dot = 0.f;
            #pragma unroll 8
            for (int k = 0; k < CC; ++k) dot = __fmaf_rn(xp[k], eg[k * NE + c], dot);
            float d = __fadd_rn(__fmaf_rn(-2.f, dot, f2), e2g[c]);
            if (d < best) { best = d; bidx = c; }
        }
        #pragma unroll
        for (int m = 1; m < 64; m <<= 1) {
            float ov = __shfl_xor(best, m, 64);
            int   oi = __shfl_xor(bidx, m, 64);
            if (ov < best || (ov == best && oi < bidx)) { best = ov; bidx = oi; }
        }
        if (lane == 0) { redv[wv] = best; redi[wv] = bidx; }
        __syncthreads();
        if (tid == 0) {
            float bv = redv[0]; int bi = redi[0];
            #pragma unroll
            for (int w = 1; w < 4; ++w)
                if (redv[w] < bv || (redv[w] == bv && redi[w] < bi)) { bv = redv[w]; bi = redi[w]; }
            idxs[p] = bi;
        }
        __syncthreads();
    }

    // histogram from final indices
    if (tid < PIXB) atomicAdd(&hist[idxs[tid]], 1u);
    __syncthreads();
    unsigned int* ghist = (unsigned int*)(ws + HIST_OFF);
    for (int t = tid; t < NE; t += 256) { unsigned int c = hist[t]; if (c) atomicAdd(&ghist[t], c); }

    // epilogue: out = x~ + (q - x~), per-batch sq accumulation (x~ = hi+lo, err ~2^-18)
    float sq = 0.f;
    for (int t = tid; t < 8192; t += 256) {
        int c = t >> 7, p = t & 127;
        int sw = (p & 15) << 4;
        int code = idxs[p];
        float q = eg[c * NE + code];
        float xh = bf2f(*(const unsigned short*)(xtb + ((p * 256 + 2 * c) ^ sw)));
        float xl = bf2f(*(const unsigned short*)(xtb + ((p * 256 + 128 + 2 * c) ^ sw)));
        float xv = __fadd_rn(xh, xl);
        float d = __fsub_rn(q, xv);
        outg[xbase + (size_t)c * HWSZ + p] = __fadd_rn(xv, d);
        sq = __fmaf_rn(d, d, sq);
    }
    #pragma unroll
    for (int m = 32; m >= 1; m >>= 1) sq += __shfl_down(sq, m, 64);
    if (lane == 0) wsum[wv] = sq;
    __syncthreads();
    if (tid == 0) atomicAdd((float*)(ws + BATCH_OFF) + bb, wsum[0] + wsum[1] + wsum[2] + wsum[3]);
}

// ---- finalize: diff[32] and perplexity ----
__global__ __launch_bounds__(512) void vq_fin(const char* __restrict__ ws, float* __restrict__ outg) {
    __shared__ float acc8[8];
    const int tid = threadIdx.x, lane = tid & 63, wv = tid >> 6;
    const unsigned int* ghist = (const unsigned int*)(ws + HIST_OFF);
    float p = (float)ghist[tid] * (1.f / (float)NPIX);
    float t = p * logf(p + 1e-10f);
    #pragma unroll
    for (int m = 32; m >= 1; m >>= 1) t += __shfl_down(t, m, 64);
    if (lane == 0) acc8[wv] = t;
    __syncthreads();
    if (tid < 32) outg[8388608 + tid] = ((const float*)(ws + BATCH_OFF))[tid] * (1.f / 262144.f);
    if (tid == 0) {
        float s = 0.f;
        #pragma unroll
        for (int u = 0; u < 8; ++u) s += acc8[u];
        outg[8388640] = expf(-s);
    }
}

extern "C" void kernel_launch(void* const* d_in, const int* in_sizes, int n_in,
                              void* d_out, int out_size, void* d_ws, size_t ws_size,
                              hipStream_t stream) {
    const float* xg = (const float*)d_in[0];
    const float* eg = (const float*)d_in[1];
    float* outg = (float*)d_out;
    char* ws = (char*)d_ws;
    vq_init<<<1, 512, 0, stream>>>(eg, ws);
    vq_main<<<NPIX / PIXB, 256, 0, stream>>>(xg, eg, outg, ws);
    vq_fin<<<1, 512, 0, stream>>>(ws, outg);
}